// Round 1
// baseline (124.411 us; speedup 1.0000x reference)
//
#include <hip/hip_runtime.h>
#include <math.h>

#define NCODES 16
#define LOG2E 1.4426950408889634f

// ThermoQuantizer: per-128-group abs-mean scale, soft-quantize to uniform
// 16-level codebook via softmax over -(x_norm-c)^2/T, lerp with pressure.
//
// Key algebraic collapse (codebook = linspace(-1,1,16), uniform & symmetric):
//   prob_i ∝ exp((2 x c_i - c_i^2)/T)  (x^2 term cancels in softmax)
// Iterating codes from the end nearest sign(x), C_j = cb[15-j] (for x>=0):
//   term_j = W_j * q^j,  W_j = exp(-C_j^2/T),  q = exp(-2|x_n|*step/T) <= 1
// All terms in [0,1], nearest-code term >= exp(-1/T) -> numerically stable
// with NO max-subtraction. x<0 handled by symmetry (codebook is odd-symmetric)
// via copysign. Cost: 1 exp + ~48 fma/mul per element instead of 16 exps.
__global__ __launch_bounds__(256) void tq_kernel(
    const float* __restrict__ x,
    const float* __restrict__ cb,
    const float* __restrict__ pp,
    const float* __restrict__ tp,
    float* __restrict__ out,
    int n4)
{
    const float pressure = pp[0];
    const float Teff = tp[0] + 1e-6f;
    const float invT = 1.0f / Teff;

    // Per-thread code tables, amortized over the grid-stride loop.
    float W[NCODES], WC[NCODES];
#pragma unroll
    for (int j = 0; j < NCODES; ++j) {
        float c = cb[NCODES - 1 - j];          // descending from +1
        float w = exp2f(-c * c * invT * LOG2E);
        W[j] = w;
        WC[j] = w * c;
    }
    const float step = (cb[NCODES - 1] - cb[0]) * (1.0f / 15.0f);
    const float kq = 2.0f * step * invT * LOG2E;   // q = exp2(-|xn| * kq)

    const int stride = gridDim.x * blockDim.x;
    for (int i = blockIdx.x * blockDim.x + threadIdx.x; i < n4; i += stride) {
        float4 v = reinterpret_cast<const float4*>(x)[i];

        // Group = 128 floats = 32 consecutive lanes x float4.
        float a = fabsf(v.x) + fabsf(v.y) + fabsf(v.z) + fabsf(v.w);
#pragma unroll
        for (int m = 1; m <= 16; m <<= 1)
            a += __shfl_xor(a, m, 64);  // masks <32: stays within each 32-lane half

        const float mean_c  = fmaxf(a * (1.0f / 128.0f), 1e-5f);  // clip(mean|x|,1e-5)
        const float inv_mean = __builtin_amdgcn_rcpf(mean_c);     // = scales

        float4 o;
        float* vo = &o.x;
        const float* vi = &v.x;
#pragma unroll
        for (int e = 0; e < 4; ++e) {
            float xv = vi[e];
            float xn = fabsf(xv) * inv_mean;
            float q  = exp2f(-xn * kq);
            float p  = q;
            float num = WC[0];
            float den = W[0];
#pragma unroll
            for (int j = 1; j < NCODES; ++j) {
                num = fmaf(WC[j], p, num);
                den = fmaf(W[j], p, den);
                p *= q;
            }
            float qn = num * __builtin_amdgcn_rcpf(den);  // qx_norm for |x|
            qn = copysignf(qn, xv);                        // odd symmetry
            float qx = qn * mean_c;                        // un-normalize
            vo[e] = fmaf(pressure, qx - xv, xv);           // lerp(x, qx, pressure)
        }
        reinterpret_cast<float4*>(out)[i] = o;
    }
}

extern "C" void kernel_launch(void* const* d_in, const int* in_sizes, int n_in,
                              void* d_out, int out_size, void* d_ws, size_t ws_size,
                              hipStream_t stream)
{
    const float* x  = (const float*)d_in[0];
    const float* cb = (const float*)d_in[1];
    const float* pp = (const float*)d_in[2];  // pressure (1-elem array)
    const float* tp = (const float*)d_in[3];  // temp (1-elem array)
    float* out = (float*)d_out;

    int n4 = in_sizes[0] / 4;   // 4194304 float4s; multiple of 32 => groups align
    dim3 grid(2048), block(256);
    hipLaunchKernelGGL(tq_kernel, grid, block, 0, stream,
                       x, cb, pp, tp, out, n4);
}

// Round 3
// 119.439 us; speedup vs baseline: 1.0416x; 1.0416x over previous
//
#include <hip/hip_runtime.h>
#include <math.h>

#define NCODES 16
#define NHALF 8
#define LOG2E 1.4426950408889634f

typedef float f32x4 __attribute__((ext_vector_type(4)));  // clang-native, legal
                                                          // for nontemporal builtins

// ThermoQuantizer: per-128-group abs-mean scale, soft-quantize to uniform
// 16-level codebook via softmax over -(x_norm-c)^2/T, lerp with pressure.
//
// Algebraic collapse (codebook = linspace(-1,1,16), uniform & symmetric):
//   prob_i ∝ exp((2 x c_i - c_i^2)/T)  (x^2 term cancels in softmax)
// For x>=0, with codes C_j = cb[15-j] (descending from +1):
//   term_j = W_j * q^j,  W_j = exp(-C_j^2/T),  q = exp(-2|x_n|*step/T) in (0,1]
// All terms in [0,1]; nearest-code term >= exp(-1/T) -> stable, no max-sub.
// x<0 by odd symmetry (copysign).
//
// Even/odd Horner split in q2 = q*q:
//   num(q) = En(q2) + q*On(q2), den(q) = Ed(q2) + q*Od(q2)
// -> no serial power chain, 4 independent 7-fma chains per element
//    (~35 VALU ops/elem vs ~50 before), latency fully hidden.
__global__ __launch_bounds__(256) void tq_kernel(
    const float* __restrict__ x,
    const float* __restrict__ cb,
    const float* __restrict__ pp,
    const float* __restrict__ tp,
    float* __restrict__ out,
    int n4)
{
    const float pressure = pp[0];
    const float invT = 1.0f / (tp[0] + 1e-6f);

    // Per-thread code tables (even/odd in power index j), amortized over the
    // grid-stride loop. j-th code (for x>=0): C_j = cb[15-j].
    float WE[NHALF], WO[NHALF], WCE[NHALF], WCO[NHALF];
#pragma unroll
    for (int h = 0; h < NHALF; ++h) {
        float ce = cb[NCODES - 1 - 2 * h];        // j = 2h
        float co = cb[NCODES - 2 - 2 * h];        // j = 2h+1
        float we = exp2f(-ce * ce * invT * LOG2E);
        float wo = exp2f(-co * co * invT * LOG2E);
        WE[h] = we;  WCE[h] = we * ce;
        WO[h] = wo;  WCO[h] = wo * co;
    }
    const float step = (cb[NCODES - 1] - cb[0]) * (1.0f / 15.0f);
    const float kq = 2.0f * step * invT * LOG2E;   // q = exp2(-|xn| * kq)

    const int stride = gridDim.x * blockDim.x;
    for (int i = blockIdx.x * blockDim.x + threadIdx.x; i < n4; i += stride) {
        f32x4 v = reinterpret_cast<const f32x4*>(x)[i];

        // Group = 128 floats = 32 consecutive lanes x float4.
        float a = fabsf(v.x) + fabsf(v.y) + fabsf(v.z) + fabsf(v.w);
#pragma unroll
        for (int m = 1; m <= 16; m <<= 1)
            a += __shfl_xor(a, m, 64);  // masks <32: stays within 32-lane half

        const float mean_c   = fmaxf(a * (1.0f / 128.0f), 1e-5f);
        const float inv_mean = __builtin_amdgcn_rcpf(mean_c);

        f32x4 o;
#pragma unroll
        for (int e = 0; e < 4; ++e) {
            float xv = v[e];
            float xn = fabsf(xv) * inv_mean;
            float q  = exp2f(-xn * kq);
            float q2 = q * q;
            // 4 independent Horner chains of 7 fmas each.
            float en = WCE[NHALF - 1], on = WCO[NHALF - 1];
            float ed = WE[NHALF - 1],  od = WO[NHALF - 1];
#pragma unroll
            for (int h = NHALF - 2; h >= 0; --h) {
                en = fmaf(en, q2, WCE[h]);
                on = fmaf(on, q2, WCO[h]);
                ed = fmaf(ed, q2, WE[h]);
                od = fmaf(od, q2, WO[h]);
            }
            float num = fmaf(q, on, en);
            float den = fmaf(q, od, ed);
            float qn = num * __builtin_amdgcn_rcpf(den);  // qx_norm for |x|
            qn = copysignf(qn, xv);                        // odd symmetry
            float qx = qn * mean_c;                        // un-normalize
            o[e] = fmaf(pressure, qx - xv, xv);            // lerp
        }
        __builtin_nontemporal_store(o, reinterpret_cast<f32x4*>(out) + i);
    }
}

extern "C" void kernel_launch(void* const* d_in, const int* in_sizes, int n_in,
                              void* d_out, int out_size, void* d_ws, size_t ws_size,
                              hipStream_t stream)
{
    const float* x  = (const float*)d_in[0];
    const float* cb = (const float*)d_in[1];
    const float* pp = (const float*)d_in[2];  // pressure (1-elem array)
    const float* tp = (const float*)d_in[3];  // temp (1-elem array)
    float* out = (float*)d_out;

    int n4 = in_sizes[0] / 4;   // 4194304 float4s; multiple of 32 => groups align
    dim3 grid(2048), block(256);
    hipLaunchKernelGGL(tq_kernel, grid, block, 0, stream,
                       x, cb, pp, tp, out, n4);
}